// Round 13
// baseline (226.601 us; speedup 1.0000x reference)
//
#include <hip/hip_runtime.h>
#include <math.h>

// B=32, L=512, CIN=32, D=128, N=64, E=3, PL=16, ST=8, PRED=96, P=64, BC=1024
// R13 = R10 (best: 157us) with the 3 layer launches merged into ONE kernel:
// e-loop (unroll 1) around R10's layer body VERBATIM, sched_barrier(0) fences at
// loop head/tail to forbid cross-iteration liveness (R8's 236-VGPR failure mode).
// Keeps each block's 32KB h-row XCD-L2-resident across layers; saves 2 launches.
// Layer interior untouched: R9/R11/R12 proved any interior change regresses.

typedef __attribute__((ext_vector_type(8))) short bf16x8;
typedef __attribute__((ext_vector_type(4))) float f32x4;

__device__ __forceinline__ ushort f2bf(float f) {
  uint u = __float_as_uint(f);
  return (ushort)((u + 0x7FFFu + ((u >> 16) & 1u)) >> 16);
}
__device__ __forceinline__ float bf2f(ushort u) {
  return __uint_as_float((uint)u << 16);
}
__device__ __forceinline__ float gelu_t(float t) {   // tanh-form GELU (R6-validated)
  float u2 = t * (1.5957691216f + 0.0713548162726f * t * t);
  return t / (1.f + __expf(-u2));
}
// bf16 z-tile swizzle: conv reads 2-way (free), LN writes ~4-way
#define ZSB(p, d) ((p) * 128 + ((d) ^ (((p) & 15) << 3)))

// ---------------- Combined prep (weights/PE) + S4D kernel K ----------------
__global__ __launch_bounds__(256) void prep_kernel(const float* __restrict__ W_out,
                                                   const float* __restrict__ W_head,
                                                   const float* __restrict__ log_dt,
                                                   const float* __restrict__ arl,
                                                   const float* __restrict__ aimg,
                                                   const float* __restrict__ cre,
                                                   const float* __restrict__ cim,
                                                   ushort* __restrict__ wt,
                                                   ushort* __restrict__ wth,
                                                   float* __restrict__ pet,
                                                   float* __restrict__ K_all_t) {
  __shared__ ushort lbuf[12800];
  float* fbuf = (float*)lbuf;
  int bid = blockIdx.x, tid = threadIdx.x;
  if (bid < 64) {                 // W_head^T tile: wth[t][f] (96 x 8192)
    int f0 = bid << 7;
    for (int i = tid; i < 12288; i += 256) {
      int f = i / 96, t = i - f * 96;
      lbuf[f * 100 + t] = f2bf(W_head[(size_t)(f0 + f) * 96 + t]);
    }
    __syncthreads();
    for (int i = tid; i < 12288; i += 256) {
      int t = i >> 7, f = i & 127;
      wth[(size_t)t * 8192 + f0 + f] = lbuf[f * 100 + t];
    }
  } else if (bid < 67) {          // W_out^T per e: wt[e][g][h] (256 x 128)
    int e = bid - 64;
    for (int h0 = 0; h0 < 128; h0 += 32) {
      __syncthreads();
      for (int i = tid; i < 8192; i += 256) {
        int hh = i >> 8, g = i & 255;
        lbuf[hh * 260 + g] = f2bf(W_out[e * 32768 + (h0 + hh) * 256 + g]);
      }
      __syncthreads();
      for (int i = tid; i < 8192; i += 256) {
        int g = i >> 5, hh = i & 31;
        wt[(size_t)(e * 256 + g) * 128 + h0 + hh] = lbuf[hh * 260 + g];
      }
    }
  } else if (bid < 99) {          // PE table: pet[d*64+p]
    int i = (bid - 67) * 256 + tid;
    int d = i >> 6, p = i & 63;
    float freq = expf((float)(d & ~1) * (-0.0719557841f));  // -ln(10000)/128
    float ang = (float)p * freq;
    pet[i] = (d & 1) ? cosf(ang) : sinf(ang);
  } else {                        // S4D K: 96 blocks, 4 channels each
    int kb2 = bid - 99;           // 0..95
    int e = kb2 >> 5;
    int hh = ((kb2 & 31) << 2) + (tid >> 6);
    int lane = tid & 63;
    float* cr = fbuf;
    float* ci = fbuf + 256;
    float* dr = fbuf + 512;
    float* di = fbuf + 768;
    float dt = expf(log_dt[e * 128 + hh]);
    {
      int n = lane;
      size_t base = ((size_t)e * 128 + hh) * 64 + n;
      float are = -expf(arl[base]);
      float aim = aimg[base];
      float dre = are * dt, dim = aim * dt;
      float ex = expf(dre);
      float cs = cosf(dim), sn = sinf(dim);
      float er = ex * cs - 1.f, ei = ex * sn;
      float invd = 1.f / (are * are + aim * aim);
      float qr = (er * are + ei * aim) * invd;
      float qi = (ei * are - er * aim) * invd;
      float tr = cre[base], ti = cim[base];
      cr[tid] = tr * qr - ti * qi;
      ci[tid] = tr * qi + ti * qr;
      dr[tid] = dre; di[tid] = dim;
    }
    __syncthreads();
    int p = lane, g0 = (tid >> 6) << 6;
    float fp = (float)p;
    float sum = 0.f;
#pragma unroll 4
    for (int n = 0; n < 64; ++n) {
      float er = expf(dr[g0 + n] * fp);
      float ang = di[g0 + n] * fp;
      sum += er * (cr[g0 + n] * cosf(ang) - ci[g0 + n] * sinf(ang));
    }
    K_all_t[(size_t)e * 8192 + p * 128 + hh] = 2.f * sum;
  }
}

// ---------------- RevIN + patch embed -> h fp32 (BC, d*64+p) ----------------
__global__ __launch_bounds__(256) void revin_embed_kernel(const float* __restrict__ x,
                                                          const float* __restrict__ W_embed,
                                                          const float* __restrict__ pet,
                                                          float* __restrict__ h,
                                                          float* __restrict__ meanw,
                                                          float* __restrict__ stdw) {
  __shared__ float xts[528];
  __shared__ float Wel[2048];
  __shared__ float red[8];
  int bc = blockIdx.x, tid = threadIdx.x;
  int b = bc >> 5, c = bc & 31;
  int w = tid >> 6, l = tid & 63;
  const float* xb = x + (size_t)b * 16384 + c;
  float v0 = xb[(size_t)tid * 32];
  float v1 = xb[(size_t)(tid + 256) * 32];
  float s = v0 + v1, sq = v0 * v0 + v1 * v1;
#pragma unroll
  for (int off = 1; off < 64; off <<= 1) {
    s += __shfl_xor(s, off);
    sq += __shfl_xor(sq, off);
  }
  if (l == 0) { red[w] = s; red[4 + w] = sq; }
  __syncthreads();
  s = red[0] + red[1] + red[2] + red[3];
  sq = red[4] + red[5] + red[6] + red[7];
  float mu = s * (1.f / 512.f);
  float var = sq * (1.f / 512.f) - mu * mu;
  float sd = sqrtf(var + 1e-5f);
  float inv = 1.f / sd;
  if (tid == 0) { meanw[bc] = mu; stdw[bc] = sd; }
  xts[tid] = (v0 - mu) * inv;
  xts[tid + 256] = (v1 - mu) * inv;
  if (tid == 255) {
    float ev = (v1 - mu) * inv;
#pragma unroll
    for (int i = 0; i < 16; ++i) xts[512 + i] = ev;
  }
  for (int i = tid; i < 2048; i += 256) Wel[i] = W_embed[i];
  __syncthreads();

  int p = tid & 63, dg = tid >> 6;
  float xr[16];
  const float4* xf = (const float4*)xts;
#pragma unroll
  for (int i = 0; i < 4; ++i) {
    float4 a = xf[p * 2 + i];
    xr[4 * i] = a.x; xr[4 * i + 1] = a.y; xr[4 * i + 2] = a.z; xr[4 * i + 3] = a.w;
  }
  float* hrow = h + (size_t)bc * 8192;
#pragma unroll 4
  for (int dd = 0; dd < 32; ++dd) {
    int d = dg * 32 + dd;
    float acc = 0.f;
#pragma unroll
    for (int k = 0; k < 16; ++k) acc += xr[k] * Wel[k * 128 + d];
    hrow[d * 64 + p] = acc + pet[d * 64 + p];
  }
}

// ---------------- 3 S4 residual layers in one kernel (R10 body, e-loop) ----------------
__global__ __launch_bounds__(256) void layers_kernel(float* __restrict__ h,
                                                     const float* __restrict__ K_all_t,
                                                     const float* __restrict__ ln_g,
                                                     const float* __restrict__ ln_b,
                                                     const float* __restrict__ D_skip,
                                                     const ushort* __restrict__ wt,
                                                     const float* __restrict__ b_out,
                                                     ushort* __restrict__ hb) {
  __shared__ __align__(16) ushort zs[8192];   // z bf16, ZSB-swizzled [64 p][128 d]
  __shared__ __align__(16) ushort ys[8192];   // y^T bf16 [64 p][128 h], 16B-slot XOR swz
  int bc = blockIdx.x, tid = threadIdx.x;
  float* hrow = h + (size_t)bc * 8192;
  int hh = tid & 127, pg = tid >> 7;
  int w = tid >> 6, l = tid & 63, lr = l & 15, lk = l >> 4;

#pragma unroll 1
  for (int e = 0; e < 3; ++e) {
    if (e) __syncthreads();                 // prev epilogue h writes visible; zs/ys free
    __builtin_amdgcn_sched_barrier(0);      // fence: no cross-iteration code motion

    // ---- LayerNorm over D at each p (4 threads per p), h from global ----
    {
      int p = tid >> 2, sub = tid & 3;
      float hv[32];
      float ls = 0.f, lq = 0.f;
#pragma unroll
      for (int j = 0; j < 32; ++j) {
        int d = sub + 4 * j;
        float vv = hrow[d * 64 + p];
        hv[j] = vv; ls += vv; lq += vv * vv;
      }
      ls += __shfl_xor(ls, 1); ls += __shfl_xor(ls, 2);
      lq += __shfl_xor(lq, 1); lq += __shfl_xor(lq, 2);
      float lmu = ls * (1.f / 128.f);
      float lvar = lq * (1.f / 128.f) - lmu * lmu;
      float istd = rsqrtf(lvar + 1e-5f);
#pragma unroll
      for (int j = 0; j < 32; ++j) {
        int d = sub + 4 * j;
        zs[ZSB(p, d)] = f2bf((hv[j] - lmu) * istd * ln_g[e * 128 + d] + ln_b[e * 128 + d]);
      }
    }
    __builtin_amdgcn_sched_barrier(0);   // keep kr loads out of LN's live range
    // ---- K into registers (global, coalesced rows, L2-resident) ----
    float kr[64];
    {
      const float* kb = K_all_t + e * 8192 + hh;
#pragma unroll
      for (int o = 0; o < 64; ++o) kr[o] = kb[o * 128];
    }
    float dsk = D_skip[e * 128 + hh];
    __syncthreads();   // zs complete

    // ---- causal conv, interleaved p-split (thread owns p = 2j+pg) ----
    float y[32];
#pragma unroll
    for (int j = 0; j < 32; ++j) y[j] = 0.f;
    if (pg == 0) {
#pragma unroll
      for (int q = 0; q < 63; ++q) {
        float zv = bf2f(zs[ZSB(q, hh)]);
#pragma unroll
        for (int j = (q + 1) >> 1; j < 32; ++j) y[j] += zv * kr[2 * j - q];
      }
    } else {
#pragma unroll
      for (int q = 0; q < 64; ++q) {
        float zv = bf2f(zs[ZSB(q, hh)]);
#pragma unroll
        for (int j = q >> 1; j < 32; ++j) y[j] += zv * kr[2 * j + 1 - q];
      }
    }
    // skip + GELU -> ys bf16
    {
      int slot = hh >> 3;
#pragma unroll
      for (int j = 0; j < 32; ++j) {
        int p = 2 * j + pg;
        float u = bf2f(zs[ZSB(p, hh)]);
        float t = y[j] + u * dsk;
        ys[p * 128 + ((slot ^ (p & 15)) << 3) + (hh & 7)] = f2bf(gelu_t(t));
      }
    }
    __syncthreads();   // ys complete

    // ---- MFMA GLU linear: v[g][p] = sum_h Wt[g][h] * y^T[p][h] ----
    f32x4 acc[4][4];
#pragma unroll
    for (int m = 0; m < 4; ++m)
#pragma unroll
      for (int n = 0; n < 4; ++n) acc[m][n] = (f32x4){0.f, 0.f, 0.f, 0.f};
    const ushort* wbase = wt + (size_t)e * 32768;
#pragma unroll
    for (int ks = 0; ks < 4; ++ks) {
      int kofs = ks * 32 + lk * 8;
      bf16x8 a[4], bfr[4];
#pragma unroll
      for (int mf = 0; mf < 4; ++mf) {
        int gm = (mf < 2) ? (w * 32 + mf * 16) : (128 + w * 32 + (mf - 2) * 16);
        a[mf] = *(const bf16x8*)(wbase + (size_t)(gm + lr) * 128 + kofs);
      }
#pragma unroll
      for (int nf = 0; nf < 4; ++nf) {
        int p = nf * 16 + lr;
        int slot = (ks * 4 + lk) ^ (p & 15);
        bfr[nf] = *(const bf16x8*)(ys + p * 128 + slot * 8);
      }
#pragma unroll
      for (int mf = 0; mf < 4; ++mf)
#pragma unroll
        for (int nf = 0; nf < 4; ++nf)
          acc[mf][nf] = __builtin_amdgcn_mfma_f32_16x16x32_bf16(a[mf], bfr[nf], acc[mf][nf], 0, 0, 0);
    }

    // ---- epilogue: bias + GLU + residual; e<2 -> fp32 h, e==2 -> bf16 hb ----
    if (e < 2) {
#pragma unroll
      for (int mf = 0; mf < 2; ++mf)
#pragma unroll
        for (int nf = 0; nf < 4; ++nf)
#pragma unroll
          for (int r = 0; r < 4; ++r) {
            int g = w * 32 + mf * 16 + lk * 4 + r;
            int p = nf * 16 + lr;
            float vv1 = acc[mf][nf][r] + b_out[e * 256 + g];
            float vv2 = acc[mf + 2][nf][r] + b_out[e * 256 + 128 + g];
            int idx = g * 64 + p;
            hrow[idx] = hrow[idx] + vv1 / (1.f + __expf(-vv2));
          }
    } else {
      ushort* hbrow = hb + (size_t)bc * 8192;
#pragma unroll
      for (int mf = 0; mf < 2; ++mf)
#pragma unroll
        for (int nf = 0; nf < 4; ++nf)
#pragma unroll
          for (int r = 0; r < 4; ++r) {
            int g = w * 32 + mf * 16 + lk * 4 + r;
            int p = nf * 16 + lr;
            float vv1 = acc[mf][nf][r] + b_out[e * 256 + g];
            float vv2 = acc[mf + 2][nf][r] + b_out[e * 256 + 128 + g];
            int idx = g * 64 + p;
            hbrow[idx] = f2bf(hrow[idx] + vv1 / (1.f + __expf(-vv2)));
          }
    }
    __builtin_amdgcn_sched_barrier(0);      // fence: epilogue stays in this iteration
  }
}

// ---------------- Head: bf16 GEMM (1024 x 96 x 8192), grid (b, kc) = 32x16 ----------------
__global__ __launch_bounds__(256) void head_kernel(const ushort* __restrict__ hb,
                                                   const ushort* __restrict__ wth,
                                                   float* __restrict__ part) {
  __shared__ float sred[12288];   // [4 waves][32 c][96 t]
  int bid = blockIdx.x;
  int b = bid >> 4, kc = bid & 15;
  int tid = threadIdx.x, w = tid >> 6, l = tid & 63;
  int lr = l & 15, lk = l >> 4;
  int kwbase = kc * 512 + w * 128;
  f32x4 acc[2][6];
#pragma unroll
  for (int m = 0; m < 2; ++m)
#pragma unroll
    for (int n = 0; n < 6; ++n) acc[m][n] = (f32x4){0.f, 0.f, 0.f, 0.f};
#pragma unroll 2
  for (int ks = 0; ks < 4; ++ks) {
    int kb = kwbase + ks * 32 + lk * 8;
    bf16x8 a[2];
#pragma unroll
    for (int mf = 0; mf < 2; ++mf)
      a[mf] = *(const bf16x8*)(hb + (size_t)(b * 32 + mf * 16 + lr) * 8192 + kb);
#pragma unroll
    for (int nf = 0; nf < 6; ++nf) {
      bf16x8 bb = *(const bf16x8*)(wth + (size_t)(nf * 16 + lr) * 8192 + kb);
#pragma unroll
      for (int mf = 0; mf < 2; ++mf)
        acc[mf][nf] = __builtin_amdgcn_mfma_f32_16x16x32_bf16(a[mf], bb, acc[mf][nf], 0, 0, 0);
    }
  }
#pragma unroll
  for (int mf = 0; mf < 2; ++mf)
#pragma unroll
    for (int nf = 0; nf < 6; ++nf)
#pragma unroll
      for (int r = 0; r < 4; ++r) {
        int cc = mf * 16 + lk * 4 + r;
        int t = nf * 16 + lr;
        sred[w * 3072 + cc * 96 + t] = acc[mf][nf][r];
      }
  __syncthreads();
  for (int i = tid; i < 3072; i += 256) {
    float s = sred[i] + sred[3072 + i] + sred[6144 + i] + sred[9216 + i];
    part[(size_t)(kc * 32 + b) * 3072 + i] = s;
  }
}

// ---------------- Reduce partials + bias + denorm ----------------
__global__ __launch_bounds__(256) void reduce_kernel(const float* __restrict__ part,
                                                     const float* __restrict__ b_head,
                                                     const float* __restrict__ meanw,
                                                     const float* __restrict__ stdw,
                                                     float* __restrict__ out) {
  int o = blockIdx.x * 256 + threadIdx.x;
  int c = o & 31;
  int bt = o >> 5;
  int t = bt % 96;
  int b = bt / 96;
  float s = b_head[t];
#pragma unroll
  for (int fs = 0; fs < 16; ++fs)
    s += part[(((size_t)fs * 32 + b) * 32 + c) * 96 + t];
  out[o] = s * stdw[b * 32 + c] + meanw[b * 32 + c];
}

extern "C" void kernel_launch(void* const* d_in, const int* in_sizes, int n_in,
                              void* d_out, int out_size, void* d_ws, size_t ws_size,
                              hipStream_t stream) {
  const float* x_enc   = (const float*)d_in[0];
  const float* W_embed = (const float*)d_in[4];
  const float* ln_g    = (const float*)d_in[5];
  const float* ln_b    = (const float*)d_in[6];
  const float* log_dt  = (const float*)d_in[7];
  const float* arl     = (const float*)d_in[8];
  const float* aimg    = (const float*)d_in[9];
  const float* cre     = (const float*)d_in[10];
  const float* cim     = (const float*)d_in[11];
  const float* dskip   = (const float*)d_in[12];
  const float* wout    = (const float*)d_in[13];
  const float* bout    = (const float*)d_in[14];
  const float* whead   = (const float*)d_in[15];
  const float* bhead   = (const float*)d_in[16];

  float* ws    = (float*)d_ws;
  float* meanw = ws;                        // 1024
  float* stdw  = meanw + 1024;              // 1024
  float* kall  = stdw + 1024;               // 24576
  ushort* wt   = (ushort*)(kall + 24576);   // 98304 ushorts = 49152 floats
  ushort* wth  = (ushort*)(kall + 24576 + 49152);   // 786432 ushorts = 393216 floats
  float* pet   = kall + 24576 + 49152 + 393216;     // 8192
  float* h     = pet + 8192;                // 8388608 floats (fp32 residual stream)
  ushort* hb   = (ushort*)(h + 8388608);    // 8388608 ushorts
  float* partw = h;                         // alias: h dead once head runs (head reads hb)

  float* out = (float*)d_out;

  prep_kernel<<<195, 256, 0, stream>>>(wout, whead, log_dt, arl, aimg, cre, cim,
                                       wt, wth, pet, kall);
  revin_embed_kernel<<<1024, 256, 0, stream>>>(x_enc, W_embed, pet, h, meanw, stdw);
  layers_kernel<<<1024, 256, 0, stream>>>(h, kall, ln_g, ln_b, dskip, wt, bout, hb);
  head_kernel<<<512, 256, 0, stream>>>(hb, wth, partw);
  reduce_kernel<<<384, 256, 0, stream>>>(partw, bhead, meanw, stdw, out);
}

// Round 14
// 151.375 us; speedup vs baseline: 1.4969x; 1.4969x over previous
//
#include <hip/hip_runtime.h>
#include <math.h>

// B=32, L=512, CIN=32, D=128, N=64, E=3, PL=16, ST=8, PRED=96, P=64, BC=1024
// R14 = R10 (best: 157us) with the conv reformulated as f16 dot2 (v_dot2_f32_f16):
// - prep packs K into per-parity f16x2 tap-pair tables (thread loads 32 dwords, not 64 f32)
// - z stored f16, transposed [hh][pair] with dword-slot XOR swizzle (2-way reads)
// - conv = 528 fdot2 + 32 LDS b32 reads (was 1040 FMA + 96 scalar reads)
// Triangular compile-time bounds kept (R9 lesson); one z-pair live (R12 lesson);
// 3 separate layer launches kept (R8/R13: merging always lands at 236 VGPR).

typedef __attribute__((ext_vector_type(8))) short bf16x8;
typedef __attribute__((ext_vector_type(4))) float f32x4;
typedef _Float16 h2 __attribute__((ext_vector_type(2)));

__device__ __forceinline__ ushort f2bf(float f) {
  uint u = __float_as_uint(f);
  return (ushort)((u + 0x7FFFu + ((u >> 16) & 1u)) >> 16);
}
__device__ __forceinline__ float bf2f(ushort u) {
  return __uint_as_float((uint)u << 16);
}
__device__ __forceinline__ float gelu_t(float t) {   // tanh-form GELU (R6-validated)
  float u2 = t * (1.5957691216f + 0.0713548162726f * t * t);
  return t / (1.f + __expf(-u2));
}
__device__ __forceinline__ uint h2u(h2 v) { union { h2 h; uint u; } c; c.h = v; return c.u; }
__device__ __forceinline__ h2 u2h(uint v) { union { h2 h; uint u; } c; c.u = v; return c.h; }

#if defined(__has_builtin)
#if __has_builtin(__builtin_amdgcn_fdot2)
#define HAS_FDOT2 1
#endif
#endif
__device__ __forceinline__ float dot2f(h2 a, h2 b, float c) {
#ifdef HAS_FDOT2
  return __builtin_amdgcn_fdot2(a, b, c, false);
#else
  return c + (float)a[0] * (float)b[0] + (float)a[1] * (float)b[1];
#endif
}

// ---------------- Combined prep (weights/PE) + S4D kernel K (packed f16 pairs) ----------------
__global__ __launch_bounds__(256) void prep_kernel(const float* __restrict__ W_out,
                                                   const float* __restrict__ W_head,
                                                   const float* __restrict__ log_dt,
                                                   const float* __restrict__ arl,
                                                   const float* __restrict__ aimg,
                                                   const float* __restrict__ cre,
                                                   const float* __restrict__ cim,
                                                   ushort* __restrict__ wt,
                                                   ushort* __restrict__ wth,
                                                   float* __restrict__ pet,
                                                   uint* __restrict__ kpak) {
  __shared__ ushort lbuf[12800];
  float* fbuf = (float*)lbuf;
  int bid = blockIdx.x, tid = threadIdx.x;
  if (bid < 64) {                 // W_head^T tile: wth[t][f] (96 x 8192)
    int f0 = bid << 7;
    for (int i = tid; i < 12288; i += 256) {
      int f = i / 96, t = i - f * 96;
      lbuf[f * 100 + t] = f2bf(W_head[(size_t)(f0 + f) * 96 + t]);
    }
    __syncthreads();
    for (int i = tid; i < 12288; i += 256) {
      int t = i >> 7, f = i & 127;
      wth[(size_t)t * 8192 + f0 + f] = lbuf[f * 100 + t];
    }
  } else if (bid < 67) {          // W_out^T per e: wt[e][g][h] (256 x 128)
    int e = bid - 64;
    for (int h0 = 0; h0 < 128; h0 += 32) {
      __syncthreads();
      for (int i = tid; i < 8192; i += 256) {
        int hh = i >> 8, g = i & 255;
        lbuf[hh * 260 + g] = f2bf(W_out[e * 32768 + (h0 + hh) * 256 + g]);
      }
      __syncthreads();
      for (int i = tid; i < 8192; i += 256) {
        int g = i >> 5, hh = i & 31;
        wt[(size_t)(e * 256 + g) * 128 + h0 + hh] = lbuf[hh * 260 + g];
      }
    }
  } else if (bid < 99) {          // PE table: pet[d*64+p]
    int i = (bid - 67) * 256 + tid;
    int d = i >> 6, p = i & 63;
    float freq = expf((float)(d & ~1) * (-0.0719557841f));  // -ln(10000)/128
    float ang = (float)p * freq;
    pet[i] = (d & 1) ? cosf(ang) : sinf(ang);
  } else {                        // S4D K: 96 blocks, 4 channels each (1 channel/wave)
    int kb2 = bid - 99;           // 0..95
    int e = kb2 >> 5;
    int wch = tid >> 6;
    int hh = ((kb2 & 31) << 2) + wch;
    int lane = tid & 63;
    float* cr = fbuf;
    float* ci = fbuf + 256;
    float* dr = fbuf + 512;
    float* di = fbuf + 768;
    float* kk = fbuf + 1024;      // [4][64] taps
    float dt = expf(log_dt[e * 128 + hh]);
    {
      int n = lane;
      size_t base = ((size_t)e * 128 + hh) * 64 + n;
      float are = -expf(arl[base]);
      float aim = aimg[base];
      float dre = are * dt, dim = aim * dt;
      float ex = expf(dre);
      float cs = cosf(dim), sn = sinf(dim);
      float er = ex * cs - 1.f, ei = ex * sn;
      float invd = 1.f / (are * are + aim * aim);
      float qr = (er * are + ei * aim) * invd;
      float qi = (ei * are - er * aim) * invd;
      float tr = cre[base], ti = cim[base];
      cr[tid] = tr * qr - ti * qi;
      ci[tid] = tr * qi + ti * qr;
      dr[tid] = dre; di[tid] = dim;
    }
    __syncthreads();
    int p = lane, g0 = wch << 6;
    float fp = (float)p;
    float sum = 0.f;
#pragma unroll 4
    for (int n = 0; n < 64; ++n) {
      float er = expf(dr[g0 + n] * fp);
      float ang = di[g0 + n] * fp;
      sum += er * (cr[g0 + n] * cosf(ang) - ci[g0 + n] * sinf(ang));
    }
    kk[wch * 64 + p] = 2.f * sum;
    __syncthreads();
    // pack per-parity f16 tap pairs: X[t]=(K[2t],K[2t-1])  Y[t]=(K[2t+1],K[2t])
    if (lane < 32) {
      int t = lane;
      float k2t = kk[wch * 64 + 2 * t];
      float k2t1 = kk[wch * 64 + 2 * t + 1];
      float k2tm1 = t ? kk[wch * 64 + 2 * t - 1] : 0.f;
      h2 X; X[0] = (_Float16)k2t;  X[1] = (_Float16)k2tm1;
      h2 Y; Y[0] = (_Float16)k2t1; Y[1] = (_Float16)k2t;
      kpak[((size_t)(e * 2 + 0) * 32 + t) * 128 + hh] = h2u(X);
      kpak[((size_t)(e * 2 + 1) * 32 + t) * 128 + hh] = h2u(Y);
    }
  }
}

// ---------------- RevIN + patch embed -> h fp32 (BC, d*64+p) ----------------
__global__ __launch_bounds__(256) void revin_embed_kernel(const float* __restrict__ x,
                                                          const float* __restrict__ W_embed,
                                                          const float* __restrict__ pet,
                                                          float* __restrict__ h,
                                                          float* __restrict__ meanw,
                                                          float* __restrict__ stdw) {
  __shared__ float xts[528];
  __shared__ float Wel[2048];
  __shared__ float red[8];
  int bc = blockIdx.x, tid = threadIdx.x;
  int b = bc >> 5, c = bc & 31;
  int w = tid >> 6, l = tid & 63;
  const float* xb = x + (size_t)b * 16384 + c;
  float v0 = xb[(size_t)tid * 32];
  float v1 = xb[(size_t)(tid + 256) * 32];
  float s = v0 + v1, sq = v0 * v0 + v1 * v1;
#pragma unroll
  for (int off = 1; off < 64; off <<= 1) {
    s += __shfl_xor(s, off);
    sq += __shfl_xor(sq, off);
  }
  if (l == 0) { red[w] = s; red[4 + w] = sq; }
  __syncthreads();
  s = red[0] + red[1] + red[2] + red[3];
  sq = red[4] + red[5] + red[6] + red[7];
  float mu = s * (1.f / 512.f);
  float var = sq * (1.f / 512.f) - mu * mu;
  float sd = sqrtf(var + 1e-5f);
  float inv = 1.f / sd;
  if (tid == 0) { meanw[bc] = mu; stdw[bc] = sd; }
  xts[tid] = (v0 - mu) * inv;
  xts[tid + 256] = (v1 - mu) * inv;
  if (tid == 255) {
    float ev = (v1 - mu) * inv;
#pragma unroll
    for (int i = 0; i < 16; ++i) xts[512 + i] = ev;
  }
  for (int i = tid; i < 2048; i += 256) Wel[i] = W_embed[i];
  __syncthreads();

  int p = tid & 63, dg = tid >> 6;
  float xr[16];
  const float4* xf = (const float4*)xts;
#pragma unroll
  for (int i = 0; i < 4; ++i) {
    float4 a = xf[p * 2 + i];
    xr[4 * i] = a.x; xr[4 * i + 1] = a.y; xr[4 * i + 2] = a.z; xr[4 * i + 3] = a.w;
  }
  float* hrow = h + (size_t)bc * 8192;
#pragma unroll 4
  for (int dd = 0; dd < 32; ++dd) {
    int d = dg * 32 + dd;
    float acc = 0.f;
#pragma unroll
    for (int k = 0; k < 16; ++k) acc += xr[k] * Wel[k * 128 + d];
    hrow[d * 64 + p] = acc + pet[d * 64 + p];
  }
}

// ---------------- One S4 residual layer (f16 dot2 conv) ----------------
__global__ __launch_bounds__(256) void layer_kernel(float* __restrict__ h,
                                                    const uint* __restrict__ kpak,
                                                    const float* __restrict__ ln_g,
                                                    const float* __restrict__ ln_b,
                                                    const float* __restrict__ D_skip,
                                                    const ushort* __restrict__ wt,
                                                    const float* __restrict__ b_out,
                                                    ushort* __restrict__ hb,
                                                    int e) {
  __shared__ __align__(16) ushort zs[8192];   // z f16 TRANSPOSED [128 hh][64 p], dword-slot swz
  __shared__ __align__(16) ushort ys[8192];   // y^T bf16 [64 p][128 h], 16B-slot XOR swz
  int bc = blockIdx.x, tid = threadIdx.x;
  float* hrow = h + (size_t)bc * 8192;
  int hh = tid & 127, pg = tid >> 7;
  int w = tid >> 6, l = tid & 63, lr = l & 15, lk = l >> 4;

  // ---- LayerNorm over D at each p (4 threads per p); write f16 transposed-swizzled ----
  {
    int p = tid >> 2, sub = tid & 3;
    float hv[32];
    float ls = 0.f, lq = 0.f;
#pragma unroll
    for (int j = 0; j < 32; ++j) {
      int d = sub + 4 * j;
      float vv = hrow[d * 64 + p];
      hv[j] = vv; ls += vv; lq += vv * vv;
    }
    ls += __shfl_xor(ls, 1); ls += __shfl_xor(ls, 2);
    lq += __shfl_xor(lq, 1); lq += __shfl_xor(lq, 2);
    float lmu = ls * (1.f / 128.f);
    float lvar = lq * (1.f / 128.f) - lmu * lmu;
    float istd = rsqrtf(lvar + 1e-5f);
    _Float16* zh = (_Float16*)zs;
    int ph = p >> 1, pl = p & 1;
#pragma unroll
    for (int j = 0; j < 32; ++j) {
      int d = sub + 4 * j;
      float zv = (hv[j] - lmu) * istd * ln_g[e * 128 + d] + ln_b[e * 128 + d];
      zh[d * 64 + (((ph ^ ((d >> 1) & 31)) << 1) | pl)] = (_Float16)zv;
    }
  }
  __builtin_amdgcn_sched_barrier(0);   // keep K loads out of LN's live range
  // ---- packed K tap-pairs for this thread's parity: 32 dwords ----
  uint kr32[32];
  {
    const uint* kp = kpak + ((size_t)(e * 2 + pg) * 32) * 128 + hh;
#pragma unroll
    for (int t = 0; t < 32; ++t) kr32[t] = kp[t * 128];
  }
  float dsk = D_skip[e * 128 + hh];
  __syncthreads();   // zs complete

  // ---- causal conv as f16 dot2 over q-pairs (triangular, compile-time bounds) ----
  float y[32];
#pragma unroll
  for (int j = 0; j < 32; ++j) y[j] = 0.f;
  {
    const uint* zrow = (const uint*)zs + hh * 32;
    int hsw = (hh >> 1) & 31;
#pragma unroll
    for (int m = 0; m < 32; ++m) {
      h2 zp = u2h(zrow[m ^ hsw]);
#pragma unroll
      for (int j = m; j < 32; ++j)
        y[j] = dot2f(zp, u2h(kr32[j - m]), y[j]);
    }
    // skip + GELU -> ys bf16
    const _Float16* zh = (const _Float16*)zs;
    int slot = hh >> 3;
#pragma unroll
    for (int j = 0; j < 32; ++j) {
      int p = 2 * j + pg;
      float u = (float)zh[hh * 64 + (((j ^ hsw) << 1) | pg)];
      float t = y[j] + u * dsk;
      ys[p * 128 + ((slot ^ (p & 15)) << 3) + (hh & 7)] = f2bf(gelu_t(t));
    }
  }
  __syncthreads();   // ys complete

  // ---- MFMA GLU linear: v[g][p] = sum_h Wt[g][h] * y^T[p][h] ----
  f32x4 acc[4][4];
#pragma unroll
  for (int m = 0; m < 4; ++m)
#pragma unroll
    for (int n = 0; n < 4; ++n) acc[m][n] = (f32x4){0.f, 0.f, 0.f, 0.f};
  const ushort* wbase = wt + (size_t)e * 32768;
#pragma unroll
  for (int ks = 0; ks < 4; ++ks) {
    int kofs = ks * 32 + lk * 8;
    bf16x8 a[4], bfr[4];
#pragma unroll
    for (int mf = 0; mf < 4; ++mf) {
      int gm = (mf < 2) ? (w * 32 + mf * 16) : (128 + w * 32 + (mf - 2) * 16);
      a[mf] = *(const bf16x8*)(wbase + (size_t)(gm + lr) * 128 + kofs);
    }
#pragma unroll
    for (int nf = 0; nf < 4; ++nf) {
      int p = nf * 16 + lr;
      int slot = (ks * 4 + lk) ^ (p & 15);
      bfr[nf] = *(const bf16x8*)(ys + p * 128 + slot * 8);
    }
#pragma unroll
    for (int mf = 0; mf < 4; ++mf)
#pragma unroll
      for (int nf = 0; nf < 4; ++nf)
        acc[mf][nf] = __builtin_amdgcn_mfma_f32_16x16x32_bf16(a[mf], bfr[nf], acc[mf][nf], 0, 0, 0);
  }

  // ---- epilogue: bias + GLU + residual; e<2 -> fp32 h, e==2 -> bf16 hb ----
  if (e < 2) {
#pragma unroll
    for (int mf = 0; mf < 2; ++mf)
#pragma unroll
      for (int nf = 0; nf < 4; ++nf)
#pragma unroll
        for (int r = 0; r < 4; ++r) {
          int g = w * 32 + mf * 16 + lk * 4 + r;
          int p = nf * 16 + lr;
          float vv1 = acc[mf][nf][r] + b_out[e * 256 + g];
          float vv2 = acc[mf + 2][nf][r] + b_out[e * 256 + 128 + g];
          int idx = g * 64 + p;
          hrow[idx] = hrow[idx] + vv1 / (1.f + __expf(-vv2));
        }
  } else {
    ushort* hbrow = hb + (size_t)bc * 8192;
#pragma unroll
    for (int mf = 0; mf < 2; ++mf)
#pragma unroll
      for (int nf = 0; nf < 4; ++nf)
#pragma unroll
        for (int r = 0; r < 4; ++r) {
          int g = w * 32 + mf * 16 + lk * 4 + r;
          int p = nf * 16 + lr;
          float vv1 = acc[mf][nf][r] + b_out[e * 256 + g];
          float vv2 = acc[mf + 2][nf][r] + b_out[e * 256 + 128 + g];
          int idx = g * 64 + p;
          hbrow[idx] = f2bf(hrow[idx] + vv1 / (1.f + __expf(-vv2)));
        }
  }
}

// ---------------- Head: bf16 GEMM (1024 x 96 x 8192), grid (b, kc) = 32x16 ----------------
__global__ __launch_bounds__(256) void head_kernel(const ushort* __restrict__ hb,
                                                   const ushort* __restrict__ wth,
                                                   float* __restrict__ part) {
  __shared__ float sred[12288];   // [4 waves][32 c][96 t]
  int bid = blockIdx.x;
  int b = bid >> 4, kc = bid & 15;
  int tid = threadIdx.x, w = tid >> 6, l = tid & 63;
  int lr = l & 15, lk = l >> 4;
  int kwbase = kc * 512 + w * 128;
  f32x4 acc[2][6];
#pragma unroll
  for (int m = 0; m < 2; ++m)
#pragma unroll
    for (int n = 0; n < 6; ++n) acc[m][n] = (f32x4){0.f, 0.f, 0.f, 0.f};
#pragma unroll 2
  for (int ks = 0; ks < 4; ++ks) {
    int kb = kwbase + ks * 32 + lk * 8;
    bf16x8 a[2];
#pragma unroll
    for (int mf = 0; mf < 2; ++mf)
      a[mf] = *(const bf16x8*)(hb + (size_t)(b * 32 + mf * 16 + lr) * 8192 + kb);
#pragma unroll
    for (int nf = 0; nf < 6; ++nf) {
      bf16x8 bb = *(const bf16x8*)(wth + (size_t)(nf * 16 + lr) * 8192 + kb);
#pragma unroll
      for (int mf = 0; mf < 2; ++mf)
        acc[mf][nf] = __builtin_amdgcn_mfma_f32_16x16x32_bf16(a[mf], bb, acc[mf][nf], 0, 0, 0);
    }
  }
#pragma unroll
  for (int mf = 0; mf < 2; ++mf)
#pragma unroll
    for (int nf = 0; nf < 6; ++nf)
#pragma unroll
      for (int r = 0; r < 4; ++r) {
        int cc = mf * 16 + lk * 4 + r;
        int t = nf * 16 + lr;
        sred[w * 3072 + cc * 96 + t] = acc[mf][nf][r];
      }
  __syncthreads();
  for (int i = tid; i < 3072; i += 256) {
    float s = sred[i] + sred[3072 + i] + sred[6144 + i] + sred[9216 + i];
    part[(size_t)(kc * 32 + b) * 3072 + i] = s;
  }
}

// ---------------- Reduce partials + bias + denorm ----------------
__global__ __launch_bounds__(256) void reduce_kernel(const float* __restrict__ part,
                                                     const float* __restrict__ b_head,
                                                     const float* __restrict__ meanw,
                                                     const float* __restrict__ stdw,
                                                     float* __restrict__ out) {
  int o = blockIdx.x * 256 + threadIdx.x;
  int c = o & 31;
  int bt = o >> 5;
  int t = bt % 96;
  int b = bt / 96;
  float s = b_head[t];
#pragma unroll
  for (int fs = 0; fs < 16; ++fs)
    s += part[(((size_t)fs * 32 + b) * 32 + c) * 96 + t];
  out[o] = s * stdw[b * 32 + c] + meanw[b * 32 + c];
}

extern "C" void kernel_launch(void* const* d_in, const int* in_sizes, int n_in,
                              void* d_out, int out_size, void* d_ws, size_t ws_size,
                              hipStream_t stream) {
  const float* x_enc   = (const float*)d_in[0];
  const float* W_embed = (const float*)d_in[4];
  const float* ln_g    = (const float*)d_in[5];
  const float* ln_b    = (const float*)d_in[6];
  const float* log_dt  = (const float*)d_in[7];
  const float* arl     = (const float*)d_in[8];
  const float* aimg    = (const float*)d_in[9];
  const float* cre     = (const float*)d_in[10];
  const float* cim     = (const float*)d_in[11];
  const float* dskip   = (const float*)d_in[12];
  const float* wout    = (const float*)d_in[13];
  const float* bout    = (const float*)d_in[14];
  const float* whead   = (const float*)d_in[15];
  const float* bhead   = (const float*)d_in[16];

  float* ws    = (float*)d_ws;
  float* meanw = ws;                        // 1024
  float* stdw  = meanw + 1024;              // 1024
  uint* kpak   = (uint*)(stdw + 1024);      // 24576 uints (3e x 2pg x 32t x 128hh)
  ushort* wt   = (ushort*)(stdw + 1024 + 24576);    // 98304 ushorts = 49152 floats
  ushort* wth  = (ushort*)(stdw + 1024 + 24576 + 49152);  // 786432 ushorts = 393216 floats
  float* pet   = stdw + 1024 + 24576 + 49152 + 393216;    // 8192
  float* h     = pet + 8192;                // 8388608 floats (fp32 residual stream)
  ushort* hb   = (ushort*)(h + 8388608);    // 8388608 ushorts
  float* partw = h;                         // alias: h dead once head runs (head reads hb)

  float* out = (float*)d_out;

  prep_kernel<<<195, 256, 0, stream>>>(wout, whead, log_dt, arl, aimg, cre, cim,
                                       wt, wth, pet, kpak);
  revin_embed_kernel<<<1024, 256, 0, stream>>>(x_enc, W_embed, pet, h, meanw, stdw);
  for (int e = 0; e < 3; ++e)
    layer_kernel<<<1024, 256, 0, stream>>>(h, kpak, ln_g, ln_b, dskip, wt, bout, hb, e);
  head_kernel<<<512, 256, 0, stream>>>(hb, wth, partw);
  reduce_kernel<<<384, 256, 0, stream>>>(partw, bhead, meanw, stdw, out);
}